// Round 4
// baseline (153.967 us; speedup 1.0000x reference)
//
#include <hip/hip_runtime.h>

// VQ-VAE vector quantizer, MI355X gfx950 — round 8: TLP fix.
//  r5 (DMA B, 2 w/SIMD) = 63 µs; r7 (direct-L2 B, 2 w/SIMD) = 76 µs; both
//  ~6 µs MFMA-busy + ~60 µs stall => latency-bound at 2 waves/SIMD, and
//  af[4][8] (128 regs) is what pins occupancy there.
//  Fix: 32-row blocks (1024 blocks) -> af[2][8]=64 regs -> 3 waves/SIMD;
//  B staged via global_load_lds into PER-WAVE private 8 KB buffers
//  (16 codes/step, amplification 1x, ZERO barriers in the main loop:
//  ds_read -> lgkmcnt(0) -> DMA next -> MFMA -> vmcnt(0)).
//  Loss stays algebraic (sum||z||^2 + sum best); z read once, z_q written once.

#define DIM      256
#define NCODES   1024
#define SPB      1024
#define ZQ_ELEMS 8388608
#define NBLK     1024      // 32768 rows / 32

typedef float f32x4  __attribute__((ext_vector_type(4)));
typedef short bf16x8 __attribute__((ext_vector_type(8)));
typedef short bf16x4 __attribute__((ext_vector_type(4)));

__device__ __forceinline__ short f2bf(float f) {
    union { float f; unsigned u; } v; v.f = f;
    unsigned r = v.u + 0x7FFFu + ((v.u >> 16) & 1u);   // RNE
    return (short)(r >> 16);
}

#define GLL16(g, l)                                                            \
    __builtin_amdgcn_global_load_lds(                                          \
        (const __attribute__((address_space(1))) void*)(g),                    \
        (__attribute__((address_space(3))) void*)(l), 16, 0, 0)

#define WAITV0    asm volatile("s_waitcnt vmcnt(0)" ::: "memory")
#define WAITLGKM0 asm volatile("s_waitcnt lgkmcnt(0)" ::: "memory")

// ---------------- K1: prep ----------------
__global__ __launch_bounds__(256) void prep(const float* __restrict__ w,
                                            short* __restrict__ wbf,
                                            float* __restrict__ wn,
                                            float* __restrict__ acc,
                                            unsigned* __restrict__ done) {
    const int t = threadIdx.x, wv = t >> 6, l = t & 63;
    const int k = blockIdx.x * 4 + wv;          // one wave per code
    const float* wr = w + (size_t)k * DIM + 4 * l;
    f32x4 v = *(const f32x4*)wr;
    bf16x4 p;
    p[0] = f2bf(v[0]); p[1] = f2bf(v[1]); p[2] = f2bf(v[2]); p[3] = f2bf(v[3]);
    *(bf16x4*)(wbf + (size_t)k * DIM + 4 * l) = p;
    float s = v[0]*v[0] + v[1]*v[1] + v[2]*v[2] + v[3]*v[3];
#pragma unroll
    for (int off = 32; off; off >>= 1) s += __shfl_down(s, off);
    if (l == 0) wn[k] = s;
    if (blockIdx.x == 0 && t == 0) { *acc = 0.f; *done = 0u; }
}

// ---------------- K2: fused gemm+argmin+gather+loss ----------------
// LDS union region smem[0..32768):
//   phase 1-2: zs bf16 [32 s][264 d]          (16896 B)
//   phase 3  : Bbuf[wave][8192 B]             (32768 B, per-wave private)
//   phase 5-6: zql fp32 32 rows x 1 KB        (32768 B; wave w's gather rows
//              overlay exactly its own Bbuf slot)
// fixed: wnl f32[1024], barrv f32[128], barri i32[128], sidx i32[32], zsq[4]
__global__ __launch_bounds__(256)
__attribute__((amdgpu_waves_per_eu(3, 4)))
void vq_fused(const float* __restrict__ z,
              const short* __restrict__ wbf,
              const float* __restrict__ wn,
              const float* __restrict__ w,
              float* __restrict__ out,
              float* __restrict__ acc,
              unsigned* __restrict__ done) {
    __shared__ __align__(16) char smem[32768];
    __shared__ __align__(16) float wnl[NCODES];
    __shared__ float barrv[128];
    __shared__ int   barri[128];
    __shared__ int   sidx[32];
    __shared__ float zsq[4];

    short* zs  = (short*)smem;     // [32 s][264 d] bf16
    float* zql = (float*)smem;     // [32 s][256 dwords], s-rotated

    const int t   = threadIdx.x;
    const int wv  = t >> 6;
    const int l   = t & 63;
    const int n16 = l & 15;
    const int q   = l >> 4;
    const int sx3 = t & 7;         // owns rows s = 4*sx3 .. 4*sx3+3 (ph 1,6)
    const int c0  = t >> 3;        // channel group: c = c0 + 32*ci

    const int n0    = blockIdx.x * 32;
    const int batch = n0 >> 10;
    const int sbase = n0 & 1023;
    const float* zb = z   + (size_t)batch * DIM * SPB + sbase;
    float*       ob = out + (size_t)batch * DIM * SPB + sbase;

    // ---- phase 1: z -> LDS as bf16 [s][d] + sum(z^2), wn -> LDS
    float lsq = 0.f;
#pragma unroll
    for (int ci = 0; ci < 8; ++ci) {
        const int c = c0 + 32 * ci;
        f32x4 v = *(const f32x4*)(zb + (size_t)c * SPB + 4 * sx3);
#pragma unroll
        for (int r = 0; r < 4; ++r) zs[(4 * sx3 + r) * 264 + c] = f2bf(v[r]);
        lsq += v[0]*v[0] + v[1]*v[1] + v[2]*v[2] + v[3]*v[3];
    }
#pragma unroll
    for (int off = 32; off; off >>= 1) lsq += __shfl_down(lsq, off);
    if (l == 0) zsq[wv] = lsq;
    *(f32x4*)&wnl[4 * t] = *(const f32x4*)(wn + 4 * t);
    __syncthreads();               // zs + wnl + zsq visible

    // ---- phase 2: A fragments, rows 16g+n16, dims 32T+8q+j (ds_read_b128)
    bf16x8 af[2][8];
#pragma unroll
    for (int g = 0; g < 2; ++g)
#pragma unroll
        for (int T = 0; T < 8; ++T)
            af[g][T] = *(const bf16x8*)((const char*)smem +
                           (16 * g + n16) * 528 + 64 * T + 16 * q);
    __syncthreads();               // zs dead; Bbuf region free for DMA

    // ---- phase 3: per-wave private B pipeline, codes [256wv, 256wv+256)
    char* Bq = smem + wv * 8192;                      // private 16-code tile
    const short* wq = wbf + ((size_t)wv << 16);       // 256*wv*DIM shorts
    // DMA source granule-XOR swizzle (r5-proven): tile granule G = 64i + l,
    // code n = G>>5, phys granule p = G&31 holds logical p^(n&7)
    int soff[8];
#pragma unroll
    for (int i = 0; i < 8; ++i) {
        const int n = 2 * i + (l >> 5);
        const int p = l & 31;
        soff[i] = n * 256 + 8 * (p ^ (n & 7));
    }
    // fragment read offsets: code n16, granule (4T+q)^(n16&7)
    int offT[8];
#pragma unroll
    for (int T = 0; T < 8; ++T)
        offT[T] = n16 * 512 + ((4 * T + q) ^ (n16 & 7)) * 16;

#pragma unroll
    for (int i = 0; i < 8; ++i) GLL16(wq + soff[i], Bq + i * 1024);

    float best[2][4];
    int   bidx[2][4];
#pragma unroll
    for (int g = 0; g < 2; ++g)
#pragma unroll
        for (int r = 0; r < 4; ++r) { best[g][r] = 3.4e38f; bidx[g][r] = 0; }
    WAITV0;                        // tile 0 landed

    for (int h = 0; h < 16; ++h) {
        bf16x8 b[8];
#pragma unroll
        for (int T = 0; T < 8; ++T) b[T] = *(const bf16x8*)(Bq + offT[T]);
        const float wk = wnl[256 * wv + 16 * h + n16];
        WAITLGKM0;                 // b,wk in regs -> safe to overwrite tile
        if (h < 15) {
            const short* gs = wq + (h + 1) * 4096;
#pragma unroll
            for (int i = 0; i < 8; ++i) GLL16(gs + soff[i], Bq + i * 1024);
        }
        f32x4 a0 = {0.f, 0.f, 0.f, 0.f};
        f32x4 a1 = {0.f, 0.f, 0.f, 0.f};
        __builtin_amdgcn_s_setprio(1);
#pragma unroll
        for (int T = 0; T < 8; ++T) {
            a0 = __builtin_amdgcn_mfma_f32_16x16x32_bf16(af[0][T], b[T], a0, 0, 0, 0);
            a1 = __builtin_amdgcn_mfma_f32_16x16x32_bf16(af[1][T], b[T], a1, 0, 0, 0);
        }
        __builtin_amdgcn_s_setprio(0);
        const int k = 256 * wv + 16 * h + n16;
#pragma unroll
        for (int r = 0; r < 4; ++r) {
            float d0 = wk - 2.f * a0[r];
            if (d0 < best[0][r]) { best[0][r] = d0; bidx[0][r] = k; }
            float d1 = wk - 2.f * a1[r];
            if (d1 < best[1][r]) { best[1][r] = d1; bidx[1][r] = k; }
        }
        if (h < 15) WAITV0;        // next tile landed
    }

    // ---- phase 4: argmin merge; acc row m = 16g + 4q + r, col = n16
#pragma unroll
    for (int g = 0; g < 2; ++g)
#pragma unroll
        for (int r = 0; r < 4; ++r) {
            float bv = best[g][r];
            int   bi = bidx[g][r];
#pragma unroll
            for (int m = 1; m < 16; m <<= 1) {
                float ov = __shfl_xor(bv, m);
                int   oi = __shfl_xor(bi, m);
                if (ov < bv || (ov == bv && oi < bi)) { bv = ov; bi = oi; }
            }
            if (n16 == 0) {
                const int row = 16 * g + 4 * q + r;
                barrv[32 * wv + row] = bv;
                barri[32 * wv + row] = bi;
            }
        }
    __syncthreads();

    float blktot = 0.f;
    if (t < 64) {                  // wave 0: merge across 4 waves
        const int row = t & 31;
        float bv = barrv[row];
        int   bi = barri[row];
#pragma unroll
        for (int w2 = 1; w2 < 4; ++w2) {
            float ov = barrv[32 * w2 + row];
            int   oi = barri[32 * w2 + row];
            if (ov < bv || (ov == bv && oi < bi)) { bv = ov; bi = oi; }
        }
        if (t < 32) sidx[row] = bi;
        float rs = (t < 32) ? bv : 0.f;
#pragma unroll
        for (int off = 32; off; off >>= 1) rs += __shfl_down(rs, off);
        if (t == 0) blktot = rs + zsq[0] + zsq[1] + zsq[2] + zsq[3];
    }
    __syncthreads();               // sidx ready; Bbuf/zs region dead

    // ---- phase 5: DMA-gather selected rows, rotated by (s>>2) granules
    // wave w writes rows 8w..8w+7 = exactly its own former Bbuf slot
#pragma unroll
    for (int i = 0; i < 8; ++i) {
        const int s  = 8 * wv + i;
        const int ks = sidx[s];
        const float* src = w + ((size_t)ks << 8) + 4 * ((l - (s >> 2)) & 63);
        GLL16(src, (char*)smem + s * 1024 + l * 16);
    }
    WAITV0;
    __syncthreads();

    // ---- phase 6: transposed z_q write; phys dword (c + 4*(s>>2)) & 255
#pragma unroll
    for (int ci = 0; ci < 8; ++ci) {
        const int c = c0 + 32 * ci;
        f32x4 qv;
#pragma unroll
        for (int r = 0; r < 4; ++r)
            qv[r] = zql[(4 * sx3 + r) * 256 + ((c + 4 * sx3) & 255)];
        __builtin_nontemporal_store(qv, (f32x4*)(ob + (size_t)c * SPB + 4 * sx3));
    }

    if (t == 0) {
        atomicAdd(acc, blktot);
        __threadfence();
        unsigned prev = atomicAdd(done, 1u);
        if (prev == NBLK - 1) {
            float val = atomicAdd(acc, 0.f) * (1.f / 8388608.f);
            out[ZQ_ELEMS]     = val;
            out[ZQ_ELEMS + 1] = val;
        }
    }
}

extern "C" void kernel_launch(void* const* d_in, const int* in_sizes, int n_in,
                              void* d_out, int out_size, void* d_ws, size_t ws_size,
                              hipStream_t stream) {
    const float* z = (const float*)d_in[0];
    const float* w = (const float*)d_in[1];
    float* out = (float*)d_out;

    char* ws = (char*)d_ws;
    short*    wbf  = (short*)ws;                   // 512 KB
    float*    wn   = (float*)(ws + 524288);        // 4 KB
    float*    acc  = (float*)(ws + 528384);
    unsigned* done = (unsigned*)(ws + 528388);

    prep<<<256, 256, 0, stream>>>(w, wbf, wn, acc, done);
    vq_fused<<<NBLK, 256, 0, stream>>>(z, wbf, wn, w, out, acc, done);
}

// Round 5
// 133.361 us; speedup vs baseline: 1.1545x; 1.1545x over previous
//
#include <hip/hip_runtime.h>

// VQ-VAE vector quantizer, MI355X gfx950 — round 9: halve codebook re-reads.
//  Evidence r5-r8: duration tracks total B (codebook) bytes through L2/L3
//  (256 MB -> 63 us, 512 MB -> 88 us); all pipes <15% busy in every variant.
//  Fix: BM=128 rows/block (256 blocks, 512 thr, 8 waves x 16 rows) -> B
//  traffic 128 MB (half of the 63-us r5 kernel), while keeping r5's proven
//  main loop verbatim: depth-3 global_load_lds pipeline, counted vmcnt,
//  barrier-paired tiles. af stays 32 VGPRs -> no r6-style spill wall.
//  Loss algebraic: sum||z||^2 + sum(best). z read once, z_q written once.

#define DIM      256
#define NCODES   1024
#define SPB      1024
#define ZQ_ELEMS 8388608
#define NBLK     256       // 32768 rows / 128

typedef float f32x4  __attribute__((ext_vector_type(4)));
typedef short bf16x8 __attribute__((ext_vector_type(8)));
typedef short bf16x4 __attribute__((ext_vector_type(4)));

__device__ __forceinline__ short f2bf(float f) {
    union { float f; unsigned u; } v; v.f = f;
    unsigned r = v.u + 0x7FFFu + ((v.u >> 16) & 1u);   // RNE
    return (short)(r >> 16);
}

#define GLL16(g, l)                                                            \
    __builtin_amdgcn_global_load_lds(                                          \
        (const __attribute__((address_space(1))) void*)(g),                    \
        (__attribute__((address_space(3))) void*)(l), 16, 0, 0)

#define WAITV(n)  asm volatile("s_waitcnt vmcnt(" #n ")" ::: "memory")
#define WAITLGKM0 asm volatile("s_waitcnt lgkmcnt(0)" ::: "memory")

// ---------------- K1: prep ----------------
__global__ __launch_bounds__(256) void prep(const float* __restrict__ w,
                                            short* __restrict__ wbf,
                                            float* __restrict__ wn,
                                            float* __restrict__ acc,
                                            unsigned* __restrict__ done) {
    const int t = threadIdx.x, wv = t >> 6, l = t & 63;
    const int k = blockIdx.x * 4 + wv;          // one wave per code
    const float* wr = w + (size_t)k * DIM + 4 * l;
    f32x4 v = *(const f32x4*)wr;
    bf16x4 p;
    p[0] = f2bf(v[0]); p[1] = f2bf(v[1]); p[2] = f2bf(v[2]); p[3] = f2bf(v[3]);
    *(bf16x4*)(wbf + (size_t)k * DIM + 4 * l) = p;
    float s = v[0]*v[0] + v[1]*v[1] + v[2]*v[2] + v[3]*v[3];
#pragma unroll
    for (int off = 32; off; off >>= 1) s += __shfl_down(s, off);
    if (l == 0) wn[k] = s;
    if (blockIdx.x == 0 && t == 0) { *acc = 0.f; *done = 0u; }
}

// ---------------- K2: fused gemm+argmin+gather+loss ----------------
// smem region (131072 B), overlaid in time:
//   phase 1-2: zs bf16 [256 d][140 s]  (71680 B)
//   phase 3  : B dbuf 4 tiles x 16384  (65536 B)
//   phase 5-6: zql fp32 128 rows x 1KB (131072 B)
// fixed tail: wnl f32[1024], sidx i32[128], zsq f32[8], bsum f32[8]
__global__ __launch_bounds__(512)
__attribute__((amdgpu_waves_per_eu(2, 2)))
void vq_fused(const float* __restrict__ z,
              const short* __restrict__ wbf,
              const float* __restrict__ wn,
              const float* __restrict__ w,
              float* __restrict__ out,
              float* __restrict__ acc,
              unsigned* __restrict__ done) {
    __shared__ __align__(16) char smem[131072];
    __shared__ __align__(16) float wnl[NCODES];
    __shared__ int   sidx[128];
    __shared__ float zsq[8];
    __shared__ float bsum[8];

    short* zs   = (short*)smem;    // [256 d][stride 140] bf16
    float* zql  = (float*)smem;    // [128 s][256 dwords], rotated

    const int t   = threadIdx.x;   // 0..511
    const int wv  = t >> 6;        // 0..7
    const int l   = t & 63;
    const int n16 = l & 15;
    const int q   = l >> 4;

    const int n0    = blockIdx.x * 128;
    const int batch = n0 >> 10;
    const int sbase = n0 & 1023;
    const float* zb = z   + (size_t)batch * DIM * SPB + sbase;
    float*       ob = out + (size_t)batch * DIM * SPB + sbase;

    // ---- phase 1: z -> LDS bf16 [d][s] (pad 140) + sum(z^2); wn -> LDS
    {
        const int sx = t & 31;         // f32x4 seg: s = 4sx..4sx+3
        const int cg = t >> 5;         // 16 channel groups
        float lsq = 0.f;
#pragma unroll
        for (int ci = 0; ci < 16; ++ci) {
            const int c = cg + 16 * ci;
            f32x4 v = *(const f32x4*)(zb + (size_t)c * SPB + 4 * sx);
            bf16x4 p;
            p[0] = f2bf(v[0]); p[1] = f2bf(v[1]);
            p[2] = f2bf(v[2]); p[3] = f2bf(v[3]);
            *(bf16x4*)&zs[140 * c + 4 * sx] = p;
            lsq += v[0]*v[0] + v[1]*v[1] + v[2]*v[2] + v[3]*v[3];
        }
#pragma unroll
        for (int off = 32; off; off >>= 1) lsq += __shfl_down(lsq, off);
        if (l == 0) zsq[wv] = lsq;
    }
    if (t < 256) *(f32x4*)&wnl[4 * t] = *(const f32x4*)(wn + 4 * t);
    __syncthreads();

    // ---- phase 2: A fragments; wave wv owns rows 16wv..16wv+15
    // lane (q,n16): row s = 16wv+n16, dims d = 32T+8q+j  (2-way banks: free)
    bf16x8 af[8];
#pragma unroll
    for (int T = 0; T < 8; ++T) {
        bf16x8 a;
#pragma unroll
        for (int j = 0; j < 8; ++j)
            a[j] = zs[140 * (32 * T + 8 * q + j) + 16 * wv + n16];
        af[T] = a;
    }
    __syncthreads();               // zs dead; B region free

    // ---- phase 3: r5-proven depth-3 pipeline, 32-code tiles, 4 buffers
    char* bb = smem;
    int soff[2];                   // staging src swizzle (granule-XOR)
#pragma unroll
    for (int i = 0; i < 2; ++i) {
        const int G = i * 512 + t;         // tile granule 0..1023
        const int n = G >> 5, p = G & 31;
        soff[i] = n * 256 + 8 * (p ^ (n & 7));
    }
    int offT[8];                   // frag read: code n16 (+sub*16), gran (4T+q)^
#pragma unroll
    for (int T = 0; T < 8; ++T)
        offT[T] = n16 * 512 + ((4 * T + q) ^ (n16 & 7)) * 16;

#pragma unroll
    for (int pt = 0; pt < 3; ++pt) {
        const short* gb = wbf + (size_t)pt * 8192;
        char* db = bb + pt * 16384;
#pragma unroll
        for (int i = 0; i < 2; ++i)
            GLL16(gb + soff[i], db + (i * 512 + t) * 16);
    }

    float best[4];
    int   bidx[4];
#pragma unroll
    for (int r = 0; r < 4; ++r) { best[r] = 3.4e38f; bidx[r] = 0; }

    for (int kt = 0; kt < 32; ++kt) {
        if (kt <= 28) {
            const short* gb = wbf + (size_t)(kt + 3) * 8192;
            char* db = bb + ((kt + 3) & 3) * 16384;
#pragma unroll
            for (int i = 0; i < 2; ++i)
                GLL16(gb + soff[i], db + (i * 512 + t) * 16);
            WAITV(6);              // tile kt landed; kt+1..kt+3 in flight
        } else if (kt == 29) { WAITV(4); }
        else if (kt == 30)   { WAITV(2); }
        else                 { WAITV(0); }
        __builtin_amdgcn_s_barrier();

        const int k0 = 32 * kt + n16;
        const float w0 = wnl[k0];
        const float w1 = wnl[k0 + 16];

        const char* wp = bb + (kt & 3) * 16384;
        f32x4 a0 = {0.f, 0.f, 0.f, 0.f};
        f32x4 a1 = {0.f, 0.f, 0.f, 0.f};
        __builtin_amdgcn_s_setprio(1);
#pragma unroll
        for (int T = 0; T < 8; ++T) {
            bf16x8 b0 = *(const bf16x8*)(wp + offT[T]);
            bf16x8 b1 = *(const bf16x8*)(wp + 8192 + offT[T]);
            a0 = __builtin_amdgcn_mfma_f32_16x16x32_bf16(af[T], b0, a0, 0, 0, 0);
            a1 = __builtin_amdgcn_mfma_f32_16x16x32_bf16(af[T], b1, a1, 0, 0, 0);
        }
        __builtin_amdgcn_s_setprio(0);
#pragma unroll
        for (int r = 0; r < 4; ++r) {
            float d0 = w0 - 2.f * a0[r];
            if (d0 < best[r]) { best[r] = d0; bidx[r] = k0; }
            float d1 = w1 - 2.f * a1[r];
            if (d1 < best[r]) { best[r] = d1; bidx[r] = k0 + 16; }
        }
        WAITLGKM0;                 // all ds_reads of this buf retired
        __builtin_amdgcn_s_barrier();
    }

    // ---- phase 4: per-wave argmin (rows disjoint!); row = 16wv + 4q + r
    float rsum = 0.f;
#pragma unroll
    for (int r = 0; r < 4; ++r) {
        float bv = best[r];
        int   bi = bidx[r];
#pragma unroll
        for (int m = 1; m < 16; m <<= 1) {
            float ov = __shfl_xor(bv, m);
            int   oi = __shfl_xor(bi, m);
            if (ov < bv || (ov == bv && oi < bi)) { bv = ov; bi = oi; }
        }
        if (n16 == 0) {
            sidx[16 * wv + 4 * q + r] = bi;
            rsum += bv;            // winning distance of this row
        }
    }
#pragma unroll
    for (int off = 32; off; off >>= 1) rsum += __shfl_down(rsum, off);
    if (l == 0) bsum[wv] = rsum;
    __syncthreads();               // sidx ready; B region dead

    // ---- phase 5: DMA-gather all 128 selected rows (1 KB each), rotated
    // by (j>>2) granules: phys dword (c + 4*(j>>2)) & 255 of row j
#pragma unroll
    for (int i = 0; i < 16; ++i) {
        const int j  = 16 * wv + i;
        const int ks = sidx[j];
        const float* src = w + ((size_t)ks << 8) + 4 * ((l - (j >> 2)) & 63);
        GLL16(src, (char*)smem + j * 1024 + l * 16);
    }
    WAITV(0);
    __syncthreads();

    // ---- phase 6: transposed z_q write (banks: (cg + 4u) -> 2-way, free)
    {
        const int u  = t & 7;      // s-quad within 32-row window
        const int cg = t >> 3;     // 64 channel groups
#pragma unroll
        for (int p = 0; p < 4; ++p) {
#pragma unroll
            for (int ci = 0; ci < 4; ++ci) {
                const int c = cg + 64 * ci;
                f32x4 qv;
#pragma unroll
                for (int r = 0; r < 4; ++r)
                    qv[r] = zql[(32 * p + 4 * u + r) * 256 +
                                ((c + 32 * p + 4 * u) & 255)];
                __builtin_nontemporal_store(
                    qv, (f32x4*)(ob + (size_t)c * SPB + 32 * p + 4 * u));
            }
        }
    }

    if (t == 0) {
        float blktot = 0.f;
#pragma unroll
        for (int i = 0; i < 8; ++i) blktot += zsq[i] + bsum[i];
        atomicAdd(acc, blktot);
        __threadfence();
        unsigned prev = atomicAdd(done, 1u);
        if (prev == NBLK - 1) {
            float val = atomicAdd(acc, 0.f) * (1.f / 8388608.f);
            out[ZQ_ELEMS]     = val;
            out[ZQ_ELEMS + 1] = val;
        }
    }
}

extern "C" void kernel_launch(void* const* d_in, const int* in_sizes, int n_in,
                              void* d_out, int out_size, void* d_ws, size_t ws_size,
                              hipStream_t stream) {
    const float* z = (const float*)d_in[0];
    const float* w = (const float*)d_in[1];
    float* out = (float*)d_out;

    char* ws = (char*)d_ws;
    short*    wbf  = (short*)ws;                   // 512 KB
    float*    wn   = (float*)(ws + 524288);        // 4 KB
    float*    acc  = (float*)(ws + 528384);
    unsigned* done = (unsigned*)(ws + 528388);

    prep<<<256, 256, 0, stream>>>(w, wbf, wn, acc, done);
    vq_fused<<<NBLK, 512, 0, stream>>>(z, wbf, wn, w, out, acc, done);
}

// Round 6
// 130.580 us; speedup vs baseline: 1.1791x; 1.0213x over previous
//
#include <hip/hip_runtime.h>

// VQ-VAE vector quantizer, MI355X gfx950 — round 10: halve per-wave B ingest.
//  r5..r9 landscape: duration invariant (~60 µs) across B-traffic halving and
//  block reshaping; the invariant quantity in the fast variants is LDS
//  B-fragment reads per CU (4 MB: every wave re-reads the whole tile at
//  16 rows/wave). Fix: 8 waves = 4 row-groups x 2 code-halves, 32 rows/wave.
//  Per iteration per wave: 8 ds_read_b128 (was 16) + 16 MFMA over 2 m-tiles.
//  Device LDS B reads 1 GB -> 512 MB. Scores/argmin bit-identical to r9.
//  Everything else (phases 1,2,5,6, depth-3 DMA pipeline, counted vmcnt,
//  granule-XOR swizzles) is r9 verbatim.

#define DIM      256
#define NCODES   1024
#define SPB      1024
#define ZQ_ELEMS 8388608
#define NBLK     256       // 32768 rows / 128

typedef float f32x4  __attribute__((ext_vector_type(4)));
typedef short bf16x8 __attribute__((ext_vector_type(8)));
typedef short bf16x4 __attribute__((ext_vector_type(4)));

__device__ __forceinline__ short f2bf(float f) {
    union { float f; unsigned u; } v; v.f = f;
    unsigned r = v.u + 0x7FFFu + ((v.u >> 16) & 1u);   // RNE
    return (short)(r >> 16);
}

#define GLL16(g, l)                                                            \
    __builtin_amdgcn_global_load_lds(                                          \
        (const __attribute__((address_space(1))) void*)(g),                    \
        (__attribute__((address_space(3))) void*)(l), 16, 0, 0)

#define WAITV(n)  asm volatile("s_waitcnt vmcnt(" #n ")" ::: "memory")
#define WAITLGKM0 asm volatile("s_waitcnt lgkmcnt(0)" ::: "memory")

// ---------------- K1: prep ----------------
__global__ __launch_bounds__(256) void prep(const float* __restrict__ w,
                                            short* __restrict__ wbf,
                                            float* __restrict__ wn,
                                            float* __restrict__ acc,
                                            unsigned* __restrict__ done) {
    const int t = threadIdx.x, wv = t >> 6, l = t & 63;
    const int k = blockIdx.x * 4 + wv;          // one wave per code
    const float* wr = w + (size_t)k * DIM + 4 * l;
    f32x4 v = *(const f32x4*)wr;
    bf16x4 p;
    p[0] = f2bf(v[0]); p[1] = f2bf(v[1]); p[2] = f2bf(v[2]); p[3] = f2bf(v[3]);
    *(bf16x4*)(wbf + (size_t)k * DIM + 4 * l) = p;
    float s = v[0]*v[0] + v[1]*v[1] + v[2]*v[2] + v[3]*v[3];
#pragma unroll
    for (int off = 32; off; off >>= 1) s += __shfl_down(s, off);
    if (l == 0) wn[k] = s;
    if (blockIdx.x == 0 && t == 0) { *acc = 0.f; *done = 0u; }
}

// ---------------- K2: fused gemm+argmin+gather+loss ----------------
// smem region (131072 B), overlaid in time:
//   phase 1-2: zs bf16 [256 d][140 s]  (71680 B)
//   phase 3  : B dbuf 4 tiles x 16384  (65536 B)
//   phase 5-6: zql fp32 128 rows x 1KB (131072 B)
// fixed tail: wnl f32[1024], barrv f32[256], barri i32[256], sidx i32[128],
//             zsq f32[8], bsum f32[2]
__global__ __launch_bounds__(512)
__attribute__((amdgpu_waves_per_eu(2, 2)))
void vq_fused(const float* __restrict__ z,
              const short* __restrict__ wbf,
              const float* __restrict__ wn,
              const float* __restrict__ w,
              float* __restrict__ out,
              float* __restrict__ acc,
              unsigned* __restrict__ done) {
    __shared__ __align__(16) char smem[131072];
    __shared__ __align__(16) float wnl[NCODES];
    __shared__ float barrv[256];
    __shared__ int   barri[256];
    __shared__ int   sidx[128];
    __shared__ float zsq[8];
    __shared__ float bsum[2];

    short* zs   = (short*)smem;    // [256 d][stride 140] bf16
    float* zql  = (float*)smem;    // [128 s][256 dwords], rotated

    const int t   = threadIdx.x;   // 0..511
    const int wv  = t >> 6;        // 0..7
    const int l   = t & 63;
    const int n16 = l & 15;
    const int q   = l >> 4;
    const int wh  = wv & 1;        // code-half (0: codes n16, 1: codes n16+16)
    const int wg  = wv >> 1;       // row-group: rows 32wg..32wg+31

    const int n0    = blockIdx.x * 128;
    const int batch = n0 >> 10;
    const int sbase = n0 & 1023;
    const float* zb = z   + (size_t)batch * DIM * SPB + sbase;
    float*       ob = out + (size_t)batch * DIM * SPB + sbase;

    // ---- phase 1: z -> LDS bf16 [d][s] (pad 140) + sum(z^2); wn -> LDS
    {
        const int sx = t & 31;         // f32x4 seg: s = 4sx..4sx+3
        const int cg = t >> 5;         // 16 channel groups
        float lsq = 0.f;
#pragma unroll
        for (int ci = 0; ci < 16; ++ci) {
            const int c = cg + 16 * ci;
            f32x4 v = *(const f32x4*)(zb + (size_t)c * SPB + 4 * sx);
            bf16x4 p;
            p[0] = f2bf(v[0]); p[1] = f2bf(v[1]);
            p[2] = f2bf(v[2]); p[3] = f2bf(v[3]);
            *(bf16x4*)&zs[140 * c + 4 * sx] = p;
            lsq += v[0]*v[0] + v[1]*v[1] + v[2]*v[2] + v[3]*v[3];
        }
#pragma unroll
        for (int off = 32; off; off >>= 1) lsq += __shfl_down(lsq, off);
        if (l == 0) zsq[wv] = lsq;
    }
    if (t < 256) *(f32x4*)&wnl[4 * t] = *(const f32x4*)(wn + 4 * t);
    __syncthreads();

    // ---- phase 2: A fragments; wave (wg) owns rows 32wg..32wg+31 (2 m-tiles)
    // lane (q,n16): row = 32wg + 16g + n16, dims d = 32T+8q+j
    bf16x8 af[2][8];
#pragma unroll
    for (int g = 0; g < 2; ++g)
#pragma unroll
        for (int T = 0; T < 8; ++T) {
            bf16x8 a;
#pragma unroll
            for (int j = 0; j < 8; ++j)
                a[j] = zs[140 * (32 * T + 8 * q + j) + 32 * wg + 16 * g + n16];
            af[g][T] = a;
        }
    __syncthreads();               // zs dead; B region free

    // ---- phase 3: depth-3 DMA pipeline, 32-code tiles, 4 buffers (r9 loop)
    char* bb = smem;
    int soff[2];                   // staging src swizzle (granule-XOR)
#pragma unroll
    for (int i = 0; i < 2; ++i) {
        const int G = i * 512 + t;         // tile granule 0..1023
        const int n = G >> 5, p = G & 31;
        soff[i] = n * 256 + 8 * (p ^ (n & 7));
    }
    // frag read: code-in-tile = 16wh + n16, granule (4T+q)^(n16&7)
    int offT[8];
#pragma unroll
    for (int T = 0; T < 8; ++T)
        offT[T] = (16 * wh + n16) * 512 + ((4 * T + q) ^ (n16 & 7)) * 16;

#pragma unroll
    for (int pt = 0; pt < 3; ++pt) {
        const short* gb = wbf + (size_t)pt * 8192;
        char* db = bb + pt * 16384;
#pragma unroll
        for (int i = 0; i < 2; ++i)
            GLL16(gb + soff[i], db + (i * 512 + t) * 16);
    }

    float best[2][4];
    int   bidx[2][4];
#pragma unroll
    for (int g = 0; g < 2; ++g)
#pragma unroll
        for (int r = 0; r < 4; ++r) { best[g][r] = 3.4e38f; bidx[g][r] = 0; }

    for (int kt = 0; kt < 32; ++kt) {
        if (kt <= 28) {
            const short* gb = wbf + (size_t)(kt + 3) * 8192;
            char* db = bb + ((kt + 3) & 3) * 16384;
#pragma unroll
            for (int i = 0; i < 2; ++i)
                GLL16(gb + soff[i], db + (i * 512 + t) * 16);
            WAITV(6);              // tile kt landed; kt+1..kt+3 in flight
        } else if (kt == 29) { WAITV(4); }
        else if (kt == 30)   { WAITV(2); }
        else                 { WAITV(0); }
        __builtin_amdgcn_s_barrier();

        const int k  = 32 * kt + 16 * wh + n16;
        const float wk = wnl[k];

        const char* wp = bb + (kt & 3) * 16384;
        f32x4 a0 = {0.f, 0.f, 0.f, 0.f};
        f32x4 a1 = {0.f, 0.f, 0.f, 0.f};
        __builtin_amdgcn_s_setprio(1);
#pragma unroll
        for (int T = 0; T < 8; ++T) {
            bf16x8 b = *(const bf16x8*)(wp + offT[T]);
            a0 = __builtin_amdgcn_mfma_f32_16x16x32_bf16(af[0][T], b, a0, 0, 0, 0);
            a1 = __builtin_amdgcn_mfma_f32_16x16x32_bf16(af[1][T], b, a1, 0, 0, 0);
        }
        __builtin_amdgcn_s_setprio(0);
#pragma unroll
        for (int r = 0; r < 4; ++r) {
            float d0 = wk - 2.f * a0[r];
            if (d0 < best[0][r]) { best[0][r] = d0; bidx[0][r] = k; }
            float d1 = wk - 2.f * a1[r];
            if (d1 < best[1][r]) { best[1][r] = d1; bidx[1][r] = k; }
        }
        WAITLGKM0;                 // all ds_reads of this buf retired
        __builtin_amdgcn_s_barrier();
    }

    // ---- phase 4: argmin. Reduce over 16 code-lanes, then merge the two
    // code-half waves per row-group. Row (within block) = 32wg + 16g + 4q + r.
#pragma unroll
    for (int g = 0; g < 2; ++g)
#pragma unroll
        for (int r = 0; r < 4; ++r) {
            float bv = best[g][r];
            int   bi = bidx[g][r];
#pragma unroll
            for (int m = 1; m < 16; m <<= 1) {
                float ov = __shfl_xor(bv, m);
                int   oi = __shfl_xor(bi, m);
                if (ov < bv || (ov == bv && oi < bi)) { bv = ov; bi = oi; }
            }
            if (n16 == 0) {
                const int row = 32 * wg + 16 * g + 4 * q + r;
                barrv[128 * wh + row] = bv;
                barri[128 * wh + row] = bi;
            }
        }
    __syncthreads();

    if (t < 128) {                 // waves 0,1: merge halves, 1 thread/row
        float bv = barrv[t];
        int   bi = barri[t];
        const float ov = barrv[128 + t];
        const int   oi = barri[128 + t];
        if (ov < bv || (ov == bv && oi < bi)) { bv = ov; bi = oi; }
        sidx[t] = bi;
        float rs = bv;             // winning distance of this row
#pragma unroll
        for (int off = 32; off; off >>= 1) rs += __shfl_down(rs, off);
        if (l == 0) bsum[wv] = rs;
    }
    __syncthreads();               // sidx ready; B region dead

    // ---- phase 5: DMA-gather all 128 selected rows (1 KB each), rotated
    // by (j>>2) granules: phys dword (c + 4*(j>>2)) & 255 of row j
#pragma unroll
    for (int i = 0; i < 16; ++i) {
        const int j  = 16 * wv + i;
        const int ks = sidx[j];
        const float* src = w + ((size_t)ks << 8) + 4 * ((l - (j >> 2)) & 63);
        GLL16(src, (char*)smem + j * 1024 + l * 16);
    }
    WAITV(0);
    __syncthreads();

    // ---- phase 6: transposed z_q write (banks: 2-way, free)
    {
        const int u  = t & 7;      // s-quad within 32-row window
        const int cg = t >> 3;     // 64 channel groups
#pragma unroll
        for (int p = 0; p < 4; ++p) {
#pragma unroll
            for (int ci = 0; ci < 4; ++ci) {
                const int c = cg + 64 * ci;
                f32x4 qv;
#pragma unroll
                for (int r = 0; r < 4; ++r)
                    qv[r] = zql[(32 * p + 4 * u + r) * 256 +
                                ((c + 32 * p + 4 * u) & 255)];
                __builtin_nontemporal_store(
                    qv, (f32x4*)(ob + (size_t)c * SPB + 32 * p + 4 * u));
            }
        }
    }

    if (t == 0) {
        float blktot = bsum[0] + bsum[1];
#pragma unroll
        for (int i = 0; i < 8; ++i) blktot += zsq[i];
        atomicAdd(acc, blktot);
        __threadfence();
        unsigned prev = atomicAdd(done, 1u);
        if (prev == NBLK - 1) {
            float val = atomicAdd(acc, 0.f) * (1.f / 8388608.f);
            out[ZQ_ELEMS]     = val;
            out[ZQ_ELEMS + 1] = val;
        }
    }
}

extern "C" void kernel_launch(void* const* d_in, const int* in_sizes, int n_in,
                              void* d_out, int out_size, void* d_ws, size_t ws_size,
                              hipStream_t stream) {
    const float* z = (const float*)d_in[0];
    const float* w = (const float*)d_in[1];
    float* out = (float*)d_out;

    char* ws = (char*)d_ws;
    short*    wbf  = (short*)ws;                   // 512 KB
    float*    wn   = (float*)(ws + 524288);        // 4 KB
    float*    acc  = (float*)(ws + 528384);
    unsigned* done = (unsigned*)(ws + 528388);

    prep<<<256, 256, 0, stream>>>(w, wbf, wn, acc, done);
    vq_fused<<<NBLK, 512, 0, stream>>>(z, wbf, wn, w, out, acc, done);
}